// Round 8
// baseline (4339.551 us; speedup 1.0000x reference)
//
#include <hip/hip_runtime.h>
#include <math.h>

// ESN: B=64, T=2048, I=25, R=512, O=50, alpha=0.5
// 256 blocks x 512 threads; block=(g,b): b=blk&63, g=blk>>6 owns rows
// [g*128,(g+1)*128). W slice [128x512] fp32 in regs. Seqlock-tagged h pairs
// {h, tag=t+1} (8B single-copy atomic), double-buffered by step parity.
// R16 = split publish under the GLC write-through model.
//  Model (fits R10/R12/R14/R15): sc0/sc1-flagged stores WRITE THROUGH to
//  HBM (~1400cy retire; R12: doubling them doubled WRITE_SIZE and cost
//  +1650cy/step) and peer visibility of the tag is the write-through
//  landing (~1400cy), not L2-update. Plain (unflagged) stores are L2
//  WRITE-BACK: dirty the shared same-XCD L2, visible to peer sc0 loads in
//  ~300cy, retire fast.
//  (1) publish = PLAIN global_store_dwordx2 {h,tag} right after finalize
//      (fast visibility, fast retire -> wv0's poll vmcnt(0) drains ~0).
//  (2) safety = sc0 sc1 store of the SAME {h,tag}, deferred fire-and-forget
//      (after poll/filler). Idempotent same-addr same-data. Keeps a
//      device-visible copy EVERY step for the fallback path.
//  (3) degradation-not-hang: if plain stores aren't visible to sc0 polls,
//      the 64-try watchdog trips the sticky fallback whose sc0 sc1 loads
//      read the safety copy -> progress at ~R10 speed. Bounded loops
//      everywhere except the R5-proven fallback spin.
//  (4) skeleton = R15's verified-correct structure: x prefetch at top,
//      u_next before any store, orow on waves 1..7, lgkm-only barrier
//      (so deferred sc1 stores are NOT drained at the barrier), step-top
//      vmcnt(2) WAW guard (t-2 same-parity stores retired by in-order
//      retirement; free in steady state). wv0 polls R10-style (no
//      speculative split): its only prior store is the cheap plain one.
// ws usage: EXACTLY 512 KB (Hf only), layout identical to R5/R8/R10.

typedef float v2f __attribute__((ext_vector_type(2)));
typedef float v4f __attribute__((ext_vector_type(4)));

template<int CTRL>
__device__ __forceinline__ float dpp_add(float x) {
    int y = __builtin_amdgcn_update_dpp(0, __float_as_int(x), CTRL, 0xF, 0xF, false);
    return x + __int_as_float(y);
}
// 0xB1 quad_perm[1,0,3,2], 0x4E quad_perm[2,3,0,1], 0x124 row_ror:4,
// 0x128 row_ror:8, 0x142 row_bcast15

// PLAIN publish store: L2 write-back -> fast same-XCD visibility + retire.
__device__ __forceinline__ void store_plain8(float* p, float h, int tag) {
    v2f v; v[0] = h; v[1] = __int_as_float(tag);
    asm volatile("global_store_dwordx2 %0, %1, off"
                 :: "v"(p), "v"(v) : "memory");
}
// Safety store: sc0 sc1 write-through (device-visible copy for fallback).
__device__ __forceinline__ void store_ic8(float* p, float h, int tag) {
    v2f v; v[0] = h; v[1] = __int_as_float(tag);
    asm volatile("global_store_dwordx2 %0, %1, off sc0 sc1"
                 :: "v"(p), "v"(v) : "memory");
}
// 3 tagged 16B loads + wait in ONE asm block (R5-proven codegen shape)
__device__ __forceinline__ void load3_ic(const float* p0, const float* p1,
                                         const float* p2, v4f& a, v4f& b, v4f& c) {
    asm volatile("global_load_dwordx4 %0, %3, off sc0 sc1\n\t"
                 "global_load_dwordx4 %1, %4, off sc0 sc1\n\t"
                 "global_load_dwordx4 %2, %5, off sc0 sc1\n\t"
                 "s_waitcnt vmcnt(0)"
                 : "=&v"(a), "=&v"(b), "=&v"(c)
                 : "v"(p0), "v"(p1), "v"(p2) : "memory");
}
__device__ __forceinline__ void load3_l2(const float* p0, const float* p1,
                                         const float* p2, v4f& a, v4f& b, v4f& c) {
    asm volatile("global_load_dwordx4 %0, %3, off sc0\n\t"
                 "global_load_dwordx4 %1, %4, off sc0\n\t"
                 "global_load_dwordx4 %2, %5, off sc0\n\t"
                 "s_waitcnt vmcnt(0)"
                 : "=&v"(a), "=&v"(b), "=&v"(c)
                 : "v"(p0), "v"(p1), "v"(p2) : "memory");
}

__device__ __forceinline__ int permidx(int c) {
    return (c >> 7) * 128 + (c & 31) * 4 + ((c >> 5) & 3);
}

#define TAGS_BAD (__any((__float_as_int(d0.y) != want) | (__float_as_int(d0.w) != want) | \
                        (__float_as_int(d1.y) != want) | (__float_as_int(d1.w) != want) | \
                        (__float_as_int(d2.y) != want) | (__float_as_int(d2.w) != want)))

// lgkm-only barrier: make LDS writes visible, do NOT drain global stores
// (the deferred sc1 safety stores must stay fire-and-forget).
#define BAR_LGKM() do { \
    asm volatile("s_waitcnt lgkmcnt(0)" ::: "memory"); \
    __builtin_amdgcn_s_barrier(); } while (0)

__global__ void __launch_bounds__(512, 2)
esn_kernel(const float* __restrict__ x, const float* __restrict__ Win,
           const float* __restrict__ W, const float* __restrict__ Wout,
           float* __restrict__ out, float* __restrict__ Hf)
{
    const int b    = blockIdx.x & 63;
    const int g    = blockIdx.x >> 6;
    const int tid  = threadIdx.x;
    const int rt   = tid >> 5;      // row-tile 0..15 (8 rows each)
    const int ct   = tid & 31;      // col phase
    const int lane = tid & 63;
    const int wv   = tid >> 6;      // wave 0..7
    const int hw   = rt & 1;

    __shared__ __align__(16) float hperm[2][512];

    // ---- W slice -> registers
    v2f Wreg[64];
    {
        const int i0 = g*128 + rt*8;
        #pragma unroll
        for (int r = 0; r < 4; ++r)
        #pragma unroll
        for (int q = 0; q < 4; ++q) {
            const float* wp = W + (r*128 + q*32 + ct);
            #pragma unroll
            for (int p = 0; p < 4; ++p) {
                v2f w;
                w[0] = wp[(size_t)(i0 + 2*p    ) * 512];
                w[1] = wp[(size_t)(i0 + 2*p + 1) * 512];
                Wreg[(r*4+q)*4 + p] = w;
            }
        }
    }

    // ---- Win row for this lane's finalize row i0+(ct&7)
    const int myrow  = g*128 + rt*8 + (ct & 7);
    const int pmyrow = permidx(myrow);
    float WinR[25];
    #pragma unroll
    for (int k = 0; k < 25; ++k) WinR[k] = Win[myrow*25 + k];

    // ---- Wout fragment: orow duty on waves 1..7 (wv0 stays poll-focused)
    const int obase = g*13;
    const int ocnt  = (g == 3) ? 11 : 13;
    const int oloc  = 2*wv - 2 + hw;            // wv0 -> negative -> invalid
    const bool ovalid = (wv != 0) & (oloc >= 0) & (oloc < ocnt);
    const int oidx  = obase + (ovalid ? oloc : 0);
    float WoutR[16];
    #pragma unroll
    for (int r = 0; r < 4; ++r)
    #pragma unroll
    for (int q = 0; q < 4; ++q)
        WoutR[r*4+q] = ovalid ? Wout[oidx*512 + r*128 + q*32 + ct] : 0.f;

    hperm[0][tid] = 0.f;        // h_0 = 0
    float holdv = 0.f;
    const bool fin = (ct >= 16) & (ct < 24);

    const float* xrow = x   + (size_t)b * 2048 * 25;
    float*       orow = out + (size_t)b * 2048 * 50;
    float* HfB0 = Hf + (size_t)b * 1024;              // par-0 base (pairs)
    const int s0 = (g+1)&3, s1 = (g+2)&3, s2 = (g+3)&3;

    bool fast = true;           // sticky fast-path flag (comm wave only)

    __syncthreads();

    // u for t=0
    float u = 0.f;
    #pragma unroll
    for (int k = 0; k < 25; ++k) u = fmaf(WinR[k], xrow[k], u);

    for (int t = 0; t < 2048; ++t) {
        const int par  = t & 1;
        const int npar = par ^ 1;
        const int want = t + 1;
        float* HfN = HfB0 + (size_t)npar * 64 * 1024;

        // ---- WAW guard (all waves; free in steady state): by in-order
        // retirement, <=2 outstanding means everything older than the
        // newest 2 stores retired -> t-2's same-parity stores are done.
        asm volatile("s_waitcnt vmcnt(2)" ::: "memory");

        // ---- prefetch next x row (consumed by u_next BEFORE any store)
        float xv[25];
        {
            const int tt = (t < 2047) ? t + 1 : 2047;
            #pragma unroll
            for (int k = 0; k < 25; ++k) xv[k] = xrow[tt*25 + k];
        }

        // ---- matvec on h_t + fused output-projection partial
        v2f acc0 = {0.f,0.f}, acc1 = {0.f,0.f}, acc2 = {0.f,0.f}, acc3 = {0.f,0.f};
        float op = 0.f;
        #pragma unroll
        for (int r = 0; r < 4; ++r) {
            v4f hv = *(const v4f*)&hperm[par][r*128 + ct*4];
            #pragma unroll
            for (int q = 0; q < 4; ++q) {
                const float hs = hv[q];
                op = fmaf(WoutR[r*4+q], hs, op);
                v2f hh = {hs, hs};
                acc0 = __builtin_elementwise_fma(Wreg[(r*4+q)*4+0], hh, acc0);
                acc1 = __builtin_elementwise_fma(Wreg[(r*4+q)*4+1], hh, acc1);
                acc2 = __builtin_elementwise_fma(Wreg[(r*4+q)*4+2], hh, acc2);
                acc3 = __builtin_elementwise_fma(Wreg[(r*4+q)*4+3], hh, acc3);
            }
        }

        // ---- FULL 32-lane reduce of 8 row partials (totals land in lanes 16..31)
        float ar[8] = {acc0[0],acc0[1],acc1[0],acc1[1],acc2[0],acc2[1],acc3[0],acc3[1]};
        #pragma unroll
        for (int j = 0; j < 8; ++j) {
            ar[j] = dpp_add<0xB1>(ar[j]);
            ar[j] = dpp_add<0x4E>(ar[j]);
            ar[j] = dpp_add<0x124>(ar[j]);
            ar[j] = dpp_add<0x128>(ar[j]);
            ar[j] = dpp_add<0x142>(ar[j]);
        }

        // ---- u_{t+1} from prefetched x: its load-wait lands HERE, before
        // any store this step (no write-through drain on the load path).
        float un = 0.f;
        #pragma unroll
        for (int k = 0; k < 25; ++k) un = fmaf(WinR[k], xv[k], un);

        // ---- finalize rows i0+(ct&7) (lanes ct in [16,24)) and PUBLISH
        // with the fast plain store (L2 write-back -> ~300cy visibility).
        if (fin) {
            const int j = ct & 7;
            float y = ar[0];
            if (j == 1) y = ar[1];
            if (j == 2) y = ar[2];
            if (j == 3) y = ar[3];
            if (j == 4) y = ar[4];
            if (j == 5) y = ar[5];
            if (j == 6) y = ar[6];
            if (j == 7) y = ar[7];
            const float z  = u + y;
            const float e  = __expf(2.f * z);
            const float th = 1.f - 2.f * __builtin_amdgcn_rcpf(e + 1.f);  // tanh
            holdv = 0.5f * holdv + 0.5f * th;
            hperm[npar][pmyrow] = holdv;              // own slice via LDS
            store_plain8(&HfN[myrow*2], holdv, want); // fast publish
        }
        u = un;

        if (wv == 0) {
            // ---- comm wave: R10-shaped tagged poll. Its only prior store
            // this step is the PLAIN one (retires fast), so the poll's
            // vmcnt(0) drains ~nothing.
            const float* p0 = HfN + (s0*256 + lane*4);
            const float* p1 = HfN + (s1*256 + lane*4);
            const float* p2 = HfN + (s2*256 + lane*4);
            v4f d0, d1, d2;
            if (fast) {
                // t==0 grace: launch/preamble skew can exceed 64 tries.
                const int budget = (t == 0) ? 2048 : 64;
                int tries = 0;
                do { load3_l2(p0, p1, p2, d0, d1, d2); } while (TAGS_BAD && ++tries < budget);
                if (TAGS_BAD) fast = false;   // sticky fallback: fast path dead
            }
            if (!fast) {
                // fallback reads the sc1 safety copy (published every step)
                do { load3_ic(p0, p1, p2, d0, d1, d2); } while (TAGS_BAD);
            }
            const int c0 = s0*128 + 2*lane, c1 = s1*128 + 2*lane, c2 = s2*128 + 2*lane;
            hperm[npar][permidx(c0)]     = d0.x;
            hperm[npar][permidx(c0 + 1)] = d0.z;
            hperm[npar][permidx(c1)]     = d1.x;
            hperm[npar][permidx(c1 + 1)] = d1.z;
            hperm[npar][permidx(c2)]     = d2.x;
            hperm[npar][permidx(c2 + 1)] = d2.z;
            // deferred safety copy (fire-and-forget; drained by next-step
            // WAW guard / poll naturally, never at a barrier)
            if (fin) store_ic8(&HfN[myrow*2], holdv, want);
        } else {
            // ---- waves 1..7: out[t-1] projection emit, then the deferred
            // sc1 safety copy (both fire-and-forget).
            op = dpp_add<0xB1>(op);  op = dpp_add<0x4E>(op);
            op = dpp_add<0x124>(op); op = dpp_add<0x128>(op);
            op = dpp_add<0x142>(op);
            if (t > 0 && ovalid && ((lane & 31) == 31))
                orow[(size_t)(t-1)*50 + oidx] = op;
            if (fin) store_ic8(&HfN[myrow*2], holdv, want);
        }

        // ---- lgkm-only barrier: no global-store drain
        BAR_LGKM();
    }

    // epilogue: out[b][2047] from h_2048 (in hperm[0])
    {
        float op = 0.f;
        #pragma unroll
        for (int r = 0; r < 4; ++r) {
            v4f hv = *(const v4f*)&hperm[0][r*128 + ct*4];
            #pragma unroll
            for (int q = 0; q < 4; ++q) op = fmaf(WoutR[r*4+q], hv[q], op);
        }
        op = dpp_add<0xB1>(op);  op = dpp_add<0x4E>(op);
        op = dpp_add<0x124>(op); op = dpp_add<0x128>(op);
        op = dpp_add<0x142>(op);
        if (ovalid && ((lane & 31) == 31))
            orow[(size_t)2047*50 + oidx] = op;
    }
}

extern "C" void kernel_launch(void* const* d_in, const int* in_sizes, int n_in,
                              void* d_out, int out_size, void* d_ws, size_t ws_size,
                              hipStream_t stream)
{
    (void)in_sizes; (void)n_in; (void)out_size; (void)ws_size;
    const float* x    = (const float*)d_in[0];
    const float* Win  = (const float*)d_in[1];
    const float* W    = (const float*)d_in[2];
    const float* Wout = (const float*)d_in[3];
    float* out = (float*)d_out;
    float* Hf  = (float*)d_ws;   // [2][64][512] x {h,tag} = 512 KB (same as R5)
    esn_kernel<<<dim3(256), dim3(512), 0, stream>>>(x, Win, W, Wout, out, Hf);
}

// Round 9
// 2759.004 us; speedup vs baseline: 1.5729x; 1.5729x over previous
//
#include <hip/hip_runtime.h>
#include <math.h>

// ESN: B=64, T=2048, I=25, R=512, O=50, alpha=0.5
// 256 blocks x 512 threads; block=(g,b): b=blk&63, g=blk>>6 owns rows
// [g*128,(g+1)*128). W slice [128x512] fp32 in regs. Seqlock-tagged h pairs
// {h, tag=t+1} (8B single-copy atomic), double-buffered by step parity.
// R17 = EXACT revert to the session-best R8 kernel (2755.9us headline).
// Rationale (R9-R16 post-mortems): step = compute (~1600cy) + cross-block
// publish->poll RT (~1600cy). The __syncthreads vmcnt(0) drain PHASE-LOCKS
// all 256 blocks: every block exits the barrier with its publish visible
// device-wide, so polls succeed first-try (minimum FETCH). Six independent
// mechanisms to shorten the RT (chain interleave, t0 grace, early poll,
// double store, storer wave + lgkm-only barriers, drain removal, plain
// write-back publish) ALL regressed 1.5-2x: they de-phase the 4-block x
// 64-batch coupled pipeline, raising poll retries + straggler skew by more
// than the saved drain. W (1MB fp32) cannot fit fewer than 4 register
// files -> the exchange is inherent; this schedule is the measured floor.
//  - stores ALWAYS sc0 sc1 (system scope, R5-proven visible everywhere).
//  - comm wave tries sc0-only loads; sticky wave-uniform watchdog (64
//    retries) falls back to sc0 sc1 loads (bounded -> hang-free).
//  - op-DPP/orow/u_next sit between publish and first poll.
// ws usage: EXACTLY 512 KB (Hf only).

typedef float v2f __attribute__((ext_vector_type(2)));
typedef float v4f __attribute__((ext_vector_type(4)));

template<int CTRL>
__device__ __forceinline__ float dpp_add(float x) {
    int y = __builtin_amdgcn_update_dpp(0, __float_as_int(x), CTRL, 0xF, 0xF, false);
    return x + __int_as_float(y);
}
// 0xB1 quad_perm[1,0,3,2], 0x4E quad_perm[2,3,0,1], 0x124 row_ror:4,
// 0x128 row_ror:8, 0x142 row_bcast15

__device__ __forceinline__ void store_ic8(float* p, float h, int tag) {
    v2f v; v[0] = h; v[1] = __int_as_float(tag);
    asm volatile("global_store_dwordx2 %0, %1, off sc0 sc1"
                 :: "v"(p), "v"(v) : "memory");
}
// 3 tagged 16B loads + wait in ONE asm block (R5-proven codegen shape)
__device__ __forceinline__ void load3_ic(const float* p0, const float* p1,
                                         const float* p2, v4f& a, v4f& b, v4f& c) {
    asm volatile("global_load_dwordx4 %0, %3, off sc0 sc1\n\t"
                 "global_load_dwordx4 %1, %4, off sc0 sc1\n\t"
                 "global_load_dwordx4 %2, %5, off sc0 sc1\n\t"
                 "s_waitcnt vmcnt(0)"
                 : "=&v"(a), "=&v"(b), "=&v"(c)
                 : "v"(p0), "v"(p1), "v"(p2) : "memory");
}
__device__ __forceinline__ void load3_l2(const float* p0, const float* p1,
                                         const float* p2, v4f& a, v4f& b, v4f& c) {
    asm volatile("global_load_dwordx4 %0, %3, off sc0\n\t"
                 "global_load_dwordx4 %1, %4, off sc0\n\t"
                 "global_load_dwordx4 %2, %5, off sc0\n\t"
                 "s_waitcnt vmcnt(0)"
                 : "=&v"(a), "=&v"(b), "=&v"(c)
                 : "v"(p0), "v"(p1), "v"(p2) : "memory");
}

__device__ __forceinline__ int permidx(int c) {
    return (c >> 7) * 128 + (c & 31) * 4 + ((c >> 5) & 3);
}

#define TAGS_BAD (__any((__float_as_int(d0.y) != want) | (__float_as_int(d0.w) != want) | \
                        (__float_as_int(d1.y) != want) | (__float_as_int(d1.w) != want) | \
                        (__float_as_int(d2.y) != want) | (__float_as_int(d2.w) != want)))

__global__ void __launch_bounds__(512, 2)
esn_kernel(const float* __restrict__ x, const float* __restrict__ Win,
           const float* __restrict__ W, const float* __restrict__ Wout,
           float* __restrict__ out, float* __restrict__ Hf)
{
    const int b    = blockIdx.x & 63;
    const int g    = blockIdx.x >> 6;
    const int tid  = threadIdx.x;
    const int rt   = tid >> 5;      // row-tile 0..15 (8 rows each)
    const int ct   = tid & 31;      // col phase
    const int lane = tid & 63;
    const int wv   = tid >> 6;      // wave 0..7
    const int hw   = rt & 1;

    __shared__ __align__(16) float hperm[2][512];

    // ---- W slice -> registers
    v2f Wreg[64];
    {
        const int i0 = g*128 + rt*8;
        #pragma unroll
        for (int r = 0; r < 4; ++r)
        #pragma unroll
        for (int q = 0; q < 4; ++q) {
            const float* wp = W + (r*128 + q*32 + ct);
            #pragma unroll
            for (int p = 0; p < 4; ++p) {
                v2f w;
                w[0] = wp[(size_t)(i0 + 2*p    ) * 512];
                w[1] = wp[(size_t)(i0 + 2*p + 1) * 512];
                Wreg[(r*4+q)*4 + p] = w;
            }
        }
    }

    // ---- Win row for this lane's finalize row i0+(ct&7)
    const int myrow = g*128 + rt*8 + (ct & 7);
    float WinR[25];
    #pragma unroll
    for (int k = 0; k < 25; ++k) WinR[k] = Win[myrow*25 + k];

    // ---- Wout fragment
    const int obase = g*13;
    const int ocnt  = (g == 3) ? 11 : 13;
    const int oloc  = 2*wv + hw;
    const bool ovalid = (oloc < ocnt);
    const int oidx  = obase + (ovalid ? oloc : 0);
    float WoutR[16];
    #pragma unroll
    for (int r = 0; r < 4; ++r)
    #pragma unroll
    for (int q = 0; q < 4; ++q)
        WoutR[r*4+q] = ovalid ? Wout[oidx*512 + r*128 + q*32 + ct] : 0.f;

    hperm[0][tid] = 0.f;        // h_0 = 0
    float holdv = 0.f;
    const bool fin = (ct >= 16) & (ct < 24);

    const float* xrow = x   + (size_t)b * 2048 * 25;
    float*       orow = out + (size_t)b * 2048 * 50;
    float* HfB0 = Hf + (size_t)b * 1024;              // par-0 base (pairs)
    const int s0 = (g+1)&3, s1 = (g+2)&3, s2 = (g+3)&3;

    bool fast = true;           // sticky fast-path flag (comm wave only)

    __syncthreads();

    // u for t=0
    float u = 0.f;
    #pragma unroll
    for (int k = 0; k < 25; ++k) u = fmaf(WinR[k], xrow[k], u);

    for (int t = 0; t < 2048; ++t) {
        const int par  = t & 1;
        const int npar = par ^ 1;
        const int want = t + 1;
        float* HfN = HfB0 + (size_t)npar * 64 * 1024;

        // ---- matvec on h_t + fused output-projection partial
        v2f acc0 = {0.f,0.f}, acc1 = {0.f,0.f}, acc2 = {0.f,0.f}, acc3 = {0.f,0.f};
        float op = 0.f;
        #pragma unroll
        for (int r = 0; r < 4; ++r) {
            v4f hv = *(const v4f*)&hperm[par][r*128 + ct*4];
            #pragma unroll
            for (int q = 0; q < 4; ++q) {
                const float hs = hv[q];
                op = fmaf(WoutR[r*4+q], hs, op);
                v2f hh = {hs, hs};
                acc0 = __builtin_elementwise_fma(Wreg[(r*4+q)*4+0], hh, acc0);
                acc1 = __builtin_elementwise_fma(Wreg[(r*4+q)*4+1], hh, acc1);
                acc2 = __builtin_elementwise_fma(Wreg[(r*4+q)*4+2], hh, acc2);
                acc3 = __builtin_elementwise_fma(Wreg[(r*4+q)*4+3], hh, acc3);
            }
        }

        // ---- FULL 32-lane reduce of 8 row partials (totals land in lanes 16..31)
        float ar[8] = {acc0[0],acc0[1],acc1[0],acc1[1],acc2[0],acc2[1],acc3[0],acc3[1]};
        #pragma unroll
        for (int j = 0; j < 8; ++j) {
            ar[j] = dpp_add<0xB1>(ar[j]);
            ar[j] = dpp_add<0x4E>(ar[j]);
            ar[j] = dpp_add<0x124>(ar[j]);
            ar[j] = dpp_add<0x128>(ar[j]);
            ar[j] = dpp_add<0x142>(ar[j]);
        }

        // ---- finalize rows i0+(ct&7) (lanes ct in [16,24)), publish ASAP
        if (fin) {
            const int j = ct & 7;
            float y = ar[0];
            if (j == 1) y = ar[1];
            if (j == 2) y = ar[2];
            if (j == 3) y = ar[3];
            if (j == 4) y = ar[4];
            if (j == 5) y = ar[5];
            if (j == 6) y = ar[6];
            if (j == 7) y = ar[7];
            const float z  = u + y;
            const float e  = __expf(2.f * z);
            const float th = 1.f - 2.f * __builtin_amdgcn_rcpf(e + 1.f);  // tanh
            holdv = 0.5f * holdv + 0.5f * th;
            hperm[npar][permidx(myrow)] = holdv;          // own slice via LDS
            store_ic8(&HfN[myrow*2], holdv, want);        // ALWAYS sc0 sc1
        }

        // ---- filler (delays first poll past the store's landing):
        //      out[b][t-1] projection emit + u_{t+1}
        op = dpp_add<0xB1>(op);  op = dpp_add<0x4E>(op);
        op = dpp_add<0x124>(op); op = dpp_add<0x128>(op);
        op = dpp_add<0x142>(op);
        if (t > 0 && ovalid && ((lane & 31) == 31))
            orow[(size_t)(t-1)*50 + oidx] = op;
        {
            const int tt = (t < 2047) ? t + 1 : 2047;
            float un = 0.f;
            #pragma unroll
            for (int k = 0; k < 25; ++k) un = fmaf(WinR[k], xrow[tt*25 + k], un);
            u = un;
        }

        // ---- comm wave: tagged fetch of 3 remote slices
        if (wv == 0) {
            const float* p0 = HfN + (s0*256 + lane*4);
            const float* p1 = HfN + (s1*256 + lane*4);
            const float* p2 = HfN + (s2*256 + lane*4);
            v4f d0, d1, d2;
            if (fast) {
                int tries = 0;
                do { load3_l2(p0, p1, p2, d0, d1, d2); } while (TAGS_BAD && ++tries < 64);
                if (TAGS_BAD) fast = false;   // sticky fallback: fast path dead
            }
            if (!fast) {
                do { load3_ic(p0, p1, p2, d0, d1, d2); } while (TAGS_BAD);
            }
            const int c0 = s0*128 + 2*lane, c1 = s1*128 + 2*lane, c2 = s2*128 + 2*lane;
            hperm[npar][permidx(c0)]     = d0.x;
            hperm[npar][permidx(c0 + 1)] = d0.z;
            hperm[npar][permidx(c1)]     = d1.x;
            hperm[npar][permidx(c1 + 1)] = d1.z;
            hperm[npar][permidx(c2)]     = d2.x;
            hperm[npar][permidx(c2 + 1)] = d2.z;
        }
        __syncthreads();   // the ONLY barrier per step
    }

    // epilogue: out[b][2047] from h_2048 (in hperm[0])
    {
        float op = 0.f;
        #pragma unroll
        for (int r = 0; r < 4; ++r) {
            v4f hv = *(const v4f*)&hperm[0][r*128 + ct*4];
            #pragma unroll
            for (int q = 0; q < 4; ++q) op = fmaf(WoutR[r*4+q], hv[q], op);
        }
        op = dpp_add<0xB1>(op);  op = dpp_add<0x4E>(op);
        op = dpp_add<0x124>(op); op = dpp_add<0x128>(op);
        op = dpp_add<0x142>(op);
        if (ovalid && ((lane & 31) == 31))
            orow[(size_t)2047*50 + oidx] = op;
    }
}

extern "C" void kernel_launch(void* const* d_in, const int* in_sizes, int n_in,
                              void* d_out, int out_size, void* d_ws, size_t ws_size,
                              hipStream_t stream)
{
    (void)in_sizes; (void)n_in; (void)out_size; (void)ws_size;
    const float* x    = (const float*)d_in[0];
    const float* Win  = (const float*)d_in[1];
    const float* W    = (const float*)d_in[2];
    const float* Wout = (const float*)d_in[3];
    float* out = (float*)d_out;
    float* Hf  = (float*)d_ws;   // [2][64][512] x {h,tag} = 512 KB (same as R5)
    esn_kernel<<<dim3(256), dim3(512), 0, stream>>>(x, Win, W, Wout, out, Hf);
}